// Round 3
// baseline (365.539 us; speedup 1.0000x reference)
//
#include <hip/hip_runtime.h>
#include <math.h>

#define NB   8
#define NC   256
#define NH   80
#define NW   80
#define NHW  6400
#define GN_EPS 1e-5f

typedef __bf16 bf16;
typedef bf16 bf16x2 __attribute__((ext_vector_type(2)));
typedef bf16 bf16x4 __attribute__((ext_vector_type(4)));
typedef bf16 bf16x8 __attribute__((ext_vector_type(8)));
typedef float f32x4 __attribute__((ext_vector_type(4)));

// wA layout: [chunk][tap][coq][qq][n][c8] — fragment (chunk,tap,coq) is a
// contiguous 1024 B block read as uniform_base + lane*16 (coalesced, L2-resident).

// ---------------- prep: x -> xp (bf16, padded, ci-chunked), 4 rows/block,
//                  + gate partials; tail blocks: zero stats + repack weights ----
__global__ __launch_bounds__(256) void prep_kernel(
    const float* __restrict__ x, bf16* __restrict__ xp,
    const float* __restrict__ gw, float* __restrict__ gpart,
    const float* __restrict__ w1, const float* __restrict__ w2,
    bf16* __restrict__ wA1, bf16* __restrict__ wA2, float* __restrict__ stats)
{
    int bid = blockIdx.x;
    int tid = threadIdx.x;
    if (bid >= 5120) {                           // setup duty: 4609 blocks
        int blk = bid - 5120;
        if (blk == 0) {
            #pragma unroll
            for (int k = 0; k < 8; k++) stats[tid + k * 256] = 0.0f;
            return;
        }
        int rb = blk - 1;                        // 0..4607
        const float* w = (rb < 2304) ? w1 : w2;
        bf16* wA       = (rb < 2304) ? wA1 : wA2;
        int idx = (rb % 2304) * 256 + tid;
        int c8  = idx & 7;
        int n   = (idx >> 3) & 15;
        int qq  = (idx >> 7) & 3;
        int coq = (idx >> 9) & 15;
        int tc  = idx >> 13;                     // 0..71
        int tap = tc % 9, chunk = tc / 9;
        int ci = chunk * 32 + qq * 8 + c8;
        int co = coq * 16 + n;
        wA[idx] = (bf16)w[(size_t)(co * 256 + ci) * 9 + tap];
        return;
    }
    __shared__ float tile[8][4][88];
    int rg  = bid % 20;                          // row group (4 rows)
    int cib = (bid / 20) & 31;
    int b   = bid / 640;
    for (int u = tid; u < 640; u += 256) {       // float4 x loads
        int c8 = u / 80; int rem = u - c8 * 80;
        int rr = rem / 20; int c4 = rem - rr * 20;
        float4 v = *(const float4*)(
            x + ((size_t)(b * NC + cib * 8 + c8) * NH + rg * 4 + rr) * NW + c4 * 4);
        *(float4*)(&tile[c8][rr][c4 * 4]) = v;
    }
    __syncthreads();
    // interior pack (4 rows), bf16x8 stores
    for (int u = tid; u < 320; u += 256) {
        int rr = u / 80, col = u - rr * 80;
        bf16x8 pk;
        #pragma unroll
        for (int j = 0; j < 8; j++) pk[j] = (bf16)tile[j][rr][col];
        size_t base = (((size_t)(b * 32 + cib) * 82 + rg * 4 + rr + 1) * 82) * 8 + 8;
        *(bf16x8*)(xp + base + col * 8) = pk;
    }
    // gate partials
    if (tid < 320) {
        int rr = tid / 80, col = tid - rr * 80;
        float s = 0.0f;
        #pragma unroll
        for (int c8 = 0; c8 < 8; c8++)
            s = fmaf(tile[c8][rr][col], gw[cib * 8 + c8], s);
        gpart[((size_t)cib * NB + b) * NHW + (rg * 4 + rr) * 80 + col] = s;
    }
    // halo zeroing
    const uint4 z4 = make_uint4(0u, 0u, 0u, 0u);
    size_t img = ((size_t)(b * 32 + cib)) * 82;
    if (tid < 8) {
        int rr = tid >> 1, col = (tid & 1) * 81;
        *(uint4*)(xp + ((img + rg * 4 + rr + 1) * 82 + col) * 8) = z4;
    }
    if (rg == 0 || rg == 19) {
        int prow = (rg == 0) ? 0 : 81;
        for (int u = tid; u < 82; u += 256)
            *(uint4*)(xp + ((img + prow) * 82 + u) * 8) = z4;
    }
}

// ---------------- conv: implicit GEMM; A and B both direct from global ----------
// block = 64co x 4rows x 80px, 4 waves (wave = one output row)
// No LDS staging, no main-loop barriers: weights are L2-resident (294 KB/ct);
// waves free-run and desync for latency hiding; 4 blocks/CU at <=128 VGPR.
__global__ __launch_bounds__(256, 4) void conv_kernel(
    const bf16* __restrict__ xp, const bf16* __restrict__ wA,
    bf16* __restrict__ y, float* __restrict__ ssum, float* __restrict__ ssq)
{
    __shared__ float wgs[8], wgq[8];

    int tid  = threadIdx.x;
    int wid  = tid >> 6;            // 0..3
    int lane = tid & 63;
    int n = lane & 15, q = lane >> 4;

    int bid = blockIdx.x;
    int ct  = bid / 160;
    int t   = bid - ct * 160;
    int b   = t / 20;
    int rt  = t - b * 20;
    int co0 = ct * 64, h0 = rt * 4;

    if (tid < 8) { wgs[tid] = 0.0f; wgq[tid] = 0.0f; }
    __syncthreads();                // init visible before epilogue atomics

    f32x4 acc[4][5];
    #pragma unroll
    for (int i = 0; i < 4; i++)
        #pragma unroll
        for (int j = 0; j < 5; j++) acc[i][j] = (f32x4){0.f, 0.f, 0.f, 0.f};

    const bf16* wAl = wA + (size_t)ct * 2048 + lane * 8;

    for (int c = 0; c < 8; c++) {
        const bf16* wc = wAl + (size_t)c * 73728;
        const bf16* xq = xp + (((size_t)(b * 32 + c * 4 + q) * 82 + (h0 + wid)) * 82) * 8 + n * 8;

        bf16x8 L0[15], L1[15];
        // rows r=0, r=1 issued first (oldest in vmcnt FIFO)
        #pragma unroll
        for (int k = 0; k < 15; k++)
            L0[k] = *(const bf16x8*)(xq + ((k / 3) * 16 + (k % 3)) * 8);
        #pragma unroll
        for (int k = 0; k < 15; k++)
            L1[k] = *(const bf16x8*)(xq + (82 + (k / 3) * 16 + (k % 3)) * 8);

        // r = 0 MFMAs (A direct from global, contiguous 1 KB wave reads)
        #pragma unroll
        for (int s = 0; s < 3; s++) {
            bf16x8 af[4];
            #pragma unroll
            for (int mt = 0; mt < 4; mt++)
                af[mt] = *(const bf16x8*)(wc + s * 8192 + mt * 512);
            #pragma unroll
            for (int mt = 0; mt < 4; mt++)
                #pragma unroll
                for (int nt = 0; nt < 5; nt++)
                    acc[mt][nt] = __builtin_amdgcn_mfma_f32_16x16x32_bf16(
                        af[mt], L0[nt * 3 + s], acc[mt][nt], 0, 0, 0);
        }
        // reload L0 with row r=2
        #pragma unroll
        for (int k = 0; k < 15; k++)
            L0[k] = *(const bf16x8*)(xq + (164 + (k / 3) * 16 + (k % 3)) * 8);

        // r = 1 MFMAs
        #pragma unroll
        for (int s = 0; s < 3; s++) {
            bf16x8 af[4];
            #pragma unroll
            for (int mt = 0; mt < 4; mt++)
                af[mt] = *(const bf16x8*)(wc + (3 + s) * 8192 + mt * 512);
            #pragma unroll
            for (int mt = 0; mt < 4; mt++)
                #pragma unroll
                for (int nt = 0; nt < 5; nt++)
                    acc[mt][nt] = __builtin_amdgcn_mfma_f32_16x16x32_bf16(
                        af[mt], L1[nt * 3 + s], acc[mt][nt], 0, 0, 0);
        }
        // r = 2 MFMAs
        #pragma unroll
        for (int s = 0; s < 3; s++) {
            bf16x8 af[4];
            #pragma unroll
            for (int mt = 0; mt < 4; mt++)
                af[mt] = *(const bf16x8*)(wc + (6 + s) * 8192 + mt * 512);
            #pragma unroll
            for (int mt = 0; mt < 4; mt++)
                #pragma unroll
                for (int nt = 0; nt < 5; nt++)
                    acc[mt][nt] = __builtin_amdgcn_mfma_f32_16x16x32_bf16(
                        af[mt], L0[nt * 3 + s], acc[mt][nt], 0, 0, 0);
        }
    }

    // epilogue: store y (chunked bf16) + group stats
    int h = h0 + wid;
    #pragma unroll
    for (int mt = 0; mt < 4; mt++) {
        float s1 = 0.0f, s2 = 0.0f;
        int co  = co0 + mt * 16 + q * 4;
        int cib = co >> 3, c8 = co & 7;
        #pragma unroll
        for (int nt = 0; nt < 5; nt++) {
            int col = nt * 16 + n;
            bf16x4 pk;
            #pragma unroll
            for (int rg = 0; rg < 4; rg++) {
                float v = acc[mt][nt][rg];
                pk[rg] = (bf16)v;
                s1 += v;
                s2 = fmaf(v, v, s2);
            }
            *(bf16x4*)(y + ((((size_t)(b * 32 + cib) * 80 + h) * 80 + col) * 8 + c8)) = pk;
        }
        #pragma unroll
        for (int off = 1; off < 16; off <<= 1) {
            s1 += __shfl_xor(s1, off, 64);
            s2 += __shfl_xor(s2, off, 64);
        }
        if (n == 0) {
            int gl = mt * 2 + (q >> 1);
            atomicAdd(&wgs[gl], s1);
            atomicAdd(&wgq[gl], s2);
        }
    }
    __syncthreads();
    if (tid < 8) {
        atomicAdd(&ssum[b * 32 + ct * 8 + tid], wgs[tid]);
        atomicAdd(&ssq [b * 32 + ct * 8 + tid], wgq[tid]);
    }
}

// ---------------- prep2: y1 -> GN1+ReLU -> xp interior; tail blocks finalize gate -
__global__ __launch_bounds__(256) void prep2_kernel(
    const bf16* __restrict__ y, bf16* __restrict__ xp,
    const float* __restrict__ s, const float* __restrict__ sq,
    const float* __restrict__ gamma, const float* __restrict__ beta,
    const float* __restrict__ gpart, const float* __restrict__ gb,
    float* __restrict__ gate)
{
    int bid = blockIdx.x;
    if (bid >= 5120) {               // gate finalize duty: 200 blocks
        int i = (bid - 5120) * 256 + threadIdx.x;
        float gs = gb[0];
        #pragma unroll 8
        for (int k = 0; k < 32; k++) gs += gpart[(size_t)k * (NB * NHW) + i];
        gate[i] = fmaxf(tanhf(gs), 0.0f);
        return;
    }
    int b = bid / 640; int rem = bid - b * 640;
    int cib = rem / 20; int rq = rem - cib * 20;
    int gidx = b * 32 + cib;
    const float cnt = (float)(8 * NHW);
    float m  = s[gidx] / cnt;
    float vv = sq[gidx] / cnt - m * m;
    float r  = rsqrtf(vv + GN_EPS);
    float scj[8], shj[8];
    #pragma unroll
    for (int j = 0; j < 8; j++) {
        int c = cib * 8 + j;
        scj[j] = r * gamma[c];
        shj[j] = beta[c] - m * scj[j];
    }
    const bf16* src = y + (size_t)(b * 32 + cib) * 51200 + rq * 2560;
    for (int u = threadIdx.x; u < 320; u += 256) {
        int e = u * 8;
        int row = rq * 4 + e / 640;
        int w640 = e - (e / 640) * 640;
        bf16x8 iv = *(const bf16x8*)(src + e);
        bf16x8 pk;
        #pragma unroll
        for (int j = 0; j < 8; j++)
            pk[j] = (bf16)fmaxf(fmaf((float)iv[j], scj[j], shj[j]), 0.0f);
        size_t xidx = (((size_t)(b * 32 + cib) * 82 + row + 1) * 82) * 8 + 8 + w640;
        *(bf16x8*)(xp + xidx) = pk;
    }
}

// ---------------- final: out = relu(gn2(y2) * gate + x), NCHW f32 ---------------
__global__ __launch_bounds__(256) void final_kernel(
    const bf16* __restrict__ y, const float* __restrict__ x,
    const float* __restrict__ gate,
    const float* __restrict__ s, const float* __restrict__ sq,
    const float* __restrict__ gamma, const float* __restrict__ beta,
    float* __restrict__ out)
{
    __shared__ float lds[8 * 328];
    int bid = blockIdx.x;
    int b = bid / 640; int rem = bid - b * 640;
    int cib = rem / 20; int rq = rem - cib * 20;
    int gidx = b * 32 + cib;
    const float cnt = (float)(8 * NHW);
    float m  = s[gidx] / cnt;
    float vv = sq[gidx] / cnt - m * m;
    float r  = rsqrtf(vv + GN_EPS);
    float scj[8], shj[8];
    #pragma unroll
    for (int j = 0; j < 8; j++) {
        int c = cib * 8 + j;
        scj[j] = r * gamma[c];
        shj[j] = beta[c] - m * scj[j];
    }
    const bf16* src = y + (size_t)(b * 32 + cib) * 51200 + rq * 2560;
    for (int u = threadIdx.x; u < 320; u += 256) {
        bf16x8 iv = *(const bf16x8*)(src + u * 8);
        #pragma unroll
        for (int j = 0; j < 8; j++)
            lds[j * 328 + u] = fmaf((float)iv[j], scj[j], shj[j]);
    }
    __syncthreads();
    const float* gp = gate + b * NHW + rq * 320;
    for (int u = threadIdx.x; u < 640; u += 256) {
        int c8 = u / 80; int rc = (u - c8 * 80) * 4;
        int c = cib * 8 + c8;
        size_t oidx = (size_t)(b * NC + c) * NHW + rq * 320 + rc;
        float4 xv = *(const float4*)(x + oidx);
        float4 gv = *(const float4*)(gp + rc);
        float4 lv = *(const float4*)(&lds[c8 * 328 + rc]);
        float4 ov;
        ov.x = fmaxf(fmaf(lv.x, gv.x, xv.x), 0.0f);
        ov.y = fmaxf(fmaf(lv.y, gv.y, xv.y), 0.0f);
        ov.z = fmaxf(fmaf(lv.z, gv.z, xv.z), 0.0f);
        ov.w = fmaxf(fmaf(lv.w, gv.w, xv.w), 0.0f);
        *(float4*)(out + oidx) = ov;
    }
}

extern "C" void kernel_launch(void* const* d_in, const int* in_sizes, int n_in,
                              void* d_out, int out_size, void* d_ws, size_t ws_size,
                              hipStream_t stream)
{
    const float* x     = (const float*)d_in[0];
    const float* w1    = (const float*)d_in[1];
    const float* gn1_w = (const float*)d_in[2];
    const float* gn1_b = (const float*)d_in[3];
    const float* w2    = (const float*)d_in[4];
    const float* gn2_w = (const float*)d_in[5];
    const float* gn2_b = (const float*)d_in[6];
    const float* gw    = (const float*)d_in[7];
    const float* gb    = (const float*)d_in[8];

    // d_out (52.4 MB): xp scratch 27.54 MB | gpart scratch 6.55 MB | (final writes all)
    bf16*  xp    = (bf16*)d_out;
    float* gpart = (float*)((char*)d_out + 27541504);
    float* out   = (float*)d_out;

    char* wsb = (char*)d_ws;
    bf16*  y     = (bf16*)wsb;                                   // 26,214,400 B
    float* gate  = (float*)(wsb + 26214400);                     //    204,800 B
    bf16*  wA1   = (bf16*)(wsb + 26214400 + 204800);             //  1,179,648 B
    bf16*  wA2   = wA1 + 589824;                                 //  1,179,648 B
    float* stats = (float*)(wsb + 26214400 + 204800 + 2 * 1179648);
    float* s1  = stats,        * s1q = stats + 256;
    float* s2  = stats + 1024, * s2q = stats + 1280;

    prep_kernel<<<9729, 256, 0, stream>>>(x, xp, gw, gpart, w1, w2, wA1, wA2, stats);
    conv_kernel<<<640, 256, 0, stream>>>(xp, wA1, y, s1, s1q);
    prep2_kernel<<<5320, 256, 0, stream>>>(y, xp, s1, s1q, gn1_w, gn1_b, gpart, gb, gate);
    conv_kernel<<<640, 256, 0, stream>>>(xp, wA2, y, s2, s2q);
    final_kernel<<<5120, 256, 0, stream>>>(y, x, gate, s2, s2q, gn2_w, gn2_b, out);
}

// Round 4
// 268.956 us; speedup vs baseline: 1.3591x; 1.3591x over previous
//
#include <hip/hip_runtime.h>
#include <math.h>

#define NB   8
#define NC   256
#define NH   80
#define NW   80
#define NHW  6400
#define GN_EPS 1e-5f

typedef __bf16 bf16;
typedef bf16 bf16x2 __attribute__((ext_vector_type(2)));
typedef bf16 bf16x4 __attribute__((ext_vector_type(4)));
typedef bf16 bf16x8 __attribute__((ext_vector_type(8)));
typedef float f32x4 __attribute__((ext_vector_type(4)));

typedef __attribute__((address_space(1))) void gvoid;
typedef __attribute__((address_space(3))) void lvoid;
__device__ __forceinline__ void glds16(const void* g, void* l) {
    __builtin_amdgcn_global_load_lds((const gvoid*)g, (lvoid*)l, 16, 0, 0);
}

// wA layout: [chunk][tap][coq][qq][n][c8] — fragment (chunk,tap,coq) is a
// contiguous 1024 B block; glds source = uniform base + lane*16; every
// ds_read_b128 in conv is a stride-1 full-wave (conflict-free) read.
#define AW_T 2048        // elems per tap (4 mt x 512)

// ---------------- prep: x -> xp (bf16, padded, ci-chunked), 4 rows/block,
//                  + gate partials; tail blocks: zero stats + repack weights ----
__global__ __launch_bounds__(256) void prep_kernel(
    const float* __restrict__ x, bf16* __restrict__ xp,
    const float* __restrict__ gw, float* __restrict__ gpart,
    const float* __restrict__ w1, const float* __restrict__ w2,
    bf16* __restrict__ wA1, bf16* __restrict__ wA2, float* __restrict__ stats)
{
    int bid = blockIdx.x;
    int tid = threadIdx.x;
    if (bid >= 5120) {                           // setup duty: 4609 blocks
        int blk = bid - 5120;
        if (blk == 0) {
            #pragma unroll
            for (int k = 0; k < 8; k++) stats[tid + k * 256] = 0.0f;
            return;
        }
        int rb = blk - 1;                        // 0..4607
        const float* w = (rb < 2304) ? w1 : w2;
        bf16* wA       = (rb < 2304) ? wA1 : wA2;
        int idx = (rb % 2304) * 256 + tid;
        int c8  = idx & 7;
        int n   = (idx >> 3) & 15;
        int qq  = (idx >> 7) & 3;
        int coq = (idx >> 9) & 15;
        int tc  = idx >> 13;                     // 0..71
        int tap = tc % 9, chunk = tc / 9;
        int ci = chunk * 32 + qq * 8 + c8;
        int co = coq * 16 + n;
        wA[idx] = (bf16)w[(size_t)(co * 256 + ci) * 9 + tap];
        return;
    }
    __shared__ float tile[8][4][88];
    int rg  = bid % 20;                          // row group (4 rows)
    int cib = (bid / 20) & 31;
    int b   = bid / 640;
    for (int u = tid; u < 640; u += 256) {       // float4 x loads
        int c8 = u / 80; int rem = u - c8 * 80;
        int rr = rem / 20; int c4 = rem - rr * 20;
        float4 v = *(const float4*)(
            x + ((size_t)(b * NC + cib * 8 + c8) * NH + rg * 4 + rr) * NW + c4 * 4);
        *(float4*)(&tile[c8][rr][c4 * 4]) = v;
    }
    __syncthreads();
    // interior pack (4 rows), bf16x8 stores
    for (int u = tid; u < 320; u += 256) {
        int rr = u / 80, col = u - rr * 80;
        bf16x8 pk;
        #pragma unroll
        for (int j = 0; j < 8; j++) pk[j] = (bf16)tile[j][rr][col];
        size_t base = (((size_t)(b * 32 + cib) * 82 + rg * 4 + rr + 1) * 82) * 8 + 8;
        *(bf16x8*)(xp + base + col * 8) = pk;
    }
    // gate partials
    if (tid < 320) {
        int rr = tid / 80, col = tid - rr * 80;
        float s = 0.0f;
        #pragma unroll
        for (int c8 = 0; c8 < 8; c8++)
            s = fmaf(tile[c8][rr][col], gw[cib * 8 + c8], s);
        gpart[((size_t)cib * NB + b) * NHW + (rg * 4 + rr) * 80 + col] = s;
    }
    // halo zeroing
    const uint4 z4 = make_uint4(0u, 0u, 0u, 0u);
    size_t img = ((size_t)(b * 32 + cib)) * 82;
    if (tid < 8) {
        int rr = tid >> 1, col = (tid & 1) * 81;
        *(uint4*)(xp + ((img + rg * 4 + rr + 1) * 82 + col) * 8) = z4;
    }
    if (rg == 0 || rg == 19) {
        int prow = (rg == 0) ? 0 : 81;
        for (int u = tid; u < 82; u += 256)
            *(uint4*)(xp + ((img + prow) * 82 + u) * 8) = z4;
    }
}

// ---------------- conv: implicit GEMM; A via single-buffer LDS, B global -------
// block = 64co x 4rows x 80px, 4 waves (wave = one output row)
// LDS 36,928 B -> 4 blocks/CU capacity; grid 640 fully resident (2.5 blocks/CU,
// ~10 waves/CU, desynced phases). Compute section verbatim from the proven
// 116-VGPR double-buffer kernel; glds moved to a {barrier, glds, barrier} phase.
__global__ __launch_bounds__(256, 4) void conv_kernel(
    const bf16* __restrict__ xp, const bf16* __restrict__ wA,
    bf16* __restrict__ y, float* __restrict__ ssum, float* __restrict__ ssq)
{
    __shared__ __align__(16) bf16 Aw[9 * AW_T];     // 36,864 B (single buffer)
    __shared__ float wgs[8], wgq[8];

    int tid  = threadIdx.x;
    int wid  = tid >> 6;            // 0..3
    int lane = tid & 63;
    int n = lane & 15, q = lane >> 4;

    int bid = blockIdx.x;           // ct*160 + (b*20 + rt); ct-siblings same XCD
    int ct  = bid / 160;
    int t   = bid - ct * 160;
    int b   = t / 20;
    int rt  = t - b * 20;
    int co0 = ct * 64, h0 = rt * 4;

    if (tid < 8) { wgs[tid] = 0.0f; wgq[tid] = 0.0f; }

    f32x4 acc[4][5];
    #pragma unroll
    for (int i = 0; i < 4; i++)
        #pragma unroll
        for (int j = 0; j < 5; j++) acc[i][j] = (f32x4){0.f, 0.f, 0.f, 0.f};

    for (int c = 0; c < 8; c++) {
        __syncthreads();            // LDS buffer free (all waves consumed chunk c-1)
        for (int p = wid; p < 36; p += 4) {
            int tap = p >> 2, mt = p & 3;
            glds16((const char*)(wA + (((size_t)c * 9 + tap) * 16 + ct * 4 + mt) * 512) + lane * 16,
                   (char*)(Aw + tap * AW_T + mt * 512) + lane * 16);
        }
        __syncthreads();            // glds landed (vmcnt drain at barrier)

        const bf16* awc = Aw + lane * 8;
        const bf16* xq  = xp + (((size_t)(b * 32 + c * 4 + q) * 82 + (h0 + wid)) * 82) * 8 + n * 8;

        bf16x8 L0[15], L1[15];
        // rows r=0, r=1: issue BEFORE anything else (oldest in vmcnt FIFO)
        #pragma unroll
        for (int k = 0; k < 15; k++)
            L0[k] = *(const bf16x8*)(xq + ((k / 3) * 16 + (k % 3)) * 8);
        #pragma unroll
        for (int k = 0; k < 15; k++)
            L1[k] = *(const bf16x8*)(xq + (82 + (k / 3) * 16 + (k % 3)) * 8);

        // r = 0 MFMAs (waits only on L0: r1 loads may remain outstanding)
        #pragma unroll
        for (int s = 0; s < 3; s++) {
            bf16x8 af[4];
            #pragma unroll
            for (int mt = 0; mt < 4; mt++)
                af[mt] = *(const bf16x8*)(awc + s * AW_T + mt * 512);
            #pragma unroll
            for (int mt = 0; mt < 4; mt++)
                #pragma unroll
                for (int nt = 0; nt < 5; nt++)
                    acc[mt][nt] = __builtin_amdgcn_mfma_f32_16x16x32_bf16(
                        af[mt], L0[nt * 3 + s], acc[mt][nt], 0, 0, 0);
        }
        // reload L0 with row r=2
        #pragma unroll
        for (int k = 0; k < 15; k++)
            L0[k] = *(const bf16x8*)(xq + (164 + (k / 3) * 16 + (k % 3)) * 8);

        // r = 1 MFMAs
        #pragma unroll
        for (int s = 0; s < 3; s++) {
            bf16x8 af[4];
            #pragma unroll
            for (int mt = 0; mt < 4; mt++)
                af[mt] = *(const bf16x8*)(awc + (3 + s) * AW_T + mt * 512);
            #pragma unroll
            for (int mt = 0; mt < 4; mt++)
                #pragma unroll
                for (int nt = 0; nt < 5; nt++)
                    acc[mt][nt] = __builtin_amdgcn_mfma_f32_16x16x32_bf16(
                        af[mt], L1[nt * 3 + s], acc[mt][nt], 0, 0, 0);
        }
        // r = 2 MFMAs
        #pragma unroll
        for (int s = 0; s < 3; s++) {
            bf16x8 af[4];
            #pragma unroll
            for (int mt = 0; mt < 4; mt++)
                af[mt] = *(const bf16x8*)(awc + (6 + s) * AW_T + mt * 512);
            #pragma unroll
            for (int mt = 0; mt < 4; mt++)
                #pragma unroll
                for (int nt = 0; nt < 5; nt++)
                    acc[mt][nt] = __builtin_amdgcn_mfma_f32_16x16x32_bf16(
                        af[mt], L0[nt * 3 + s], acc[mt][nt], 0, 0, 0);
        }
    }

    // epilogue: store y (chunked bf16) + group stats
    int h = h0 + wid;
    #pragma unroll
    for (int mt = 0; mt < 4; mt++) {
        float s1 = 0.0f, s2 = 0.0f;
        int co  = co0 + mt * 16 + q * 4;
        int cib = co >> 3, c8 = co & 7;
        #pragma unroll
        for (int nt = 0; nt < 5; nt++) {
            int col = nt * 16 + n;
            bf16x4 pk;
            #pragma unroll
            for (int rg = 0; rg < 4; rg++) {
                float v = acc[mt][nt][rg];
                pk[rg] = (bf16)v;
                s1 += v;
                s2 = fmaf(v, v, s2);
            }
            *(bf16x4*)(y + ((((size_t)(b * 32 + cib) * 80 + h) * 80 + col) * 8 + c8)) = pk;
        }
        #pragma unroll
        for (int off = 1; off < 16; off <<= 1) {
            s1 += __shfl_xor(s1, off, 64);
            s2 += __shfl_xor(s2, off, 64);
        }
        if (n == 0) {
            int gl = mt * 2 + (q >> 1);
            atomicAdd(&wgs[gl], s1);
            atomicAdd(&wgq[gl], s2);
        }
    }
    __syncthreads();
    if (tid < 8) {
        atomicAdd(&ssum[b * 32 + ct * 8 + tid], wgs[tid]);
        atomicAdd(&ssq [b * 32 + ct * 8 + tid], wgq[tid]);
    }
}

// ---------------- prep2: y1 -> GN1+ReLU -> xp interior; tail blocks finalize gate -
__global__ __launch_bounds__(256) void prep2_kernel(
    const bf16* __restrict__ y, bf16* __restrict__ xp,
    const float* __restrict__ s, const float* __restrict__ sq,
    const float* __restrict__ gamma, const float* __restrict__ beta,
    const float* __restrict__ gpart, const float* __restrict__ gb,
    float* __restrict__ gate)
{
    int bid = blockIdx.x;
    if (bid >= 5120) {               // gate finalize duty: 200 blocks
        int i = (bid - 5120) * 256 + threadIdx.x;
        float gs = gb[0];
        #pragma unroll 8
        for (int k = 0; k < 32; k++) gs += gpart[(size_t)k * (NB * NHW) + i];
        gate[i] = fmaxf(tanhf(gs), 0.0f);
        return;
    }
    int b = bid / 640; int rem = bid - b * 640;
    int cib = rem / 20; int rq = rem - cib * 20;
    int gidx = b * 32 + cib;
    const float cnt = (float)(8 * NHW);
    float m  = s[gidx] / cnt;
    float vv = sq[gidx] / cnt - m * m;
    float r  = rsqrtf(vv + GN_EPS);
    float scj[8], shj[8];
    #pragma unroll
    for (int j = 0; j < 8; j++) {
        int c = cib * 8 + j;
        scj[j] = r * gamma[c];
        shj[j] = beta[c] - m * scj[j];
    }
    const bf16* src = y + (size_t)(b * 32 + cib) * 51200 + rq * 2560;
    for (int u = threadIdx.x; u < 320; u += 256) {
        int e = u * 8;
        int row = rq * 4 + e / 640;
        int w640 = e - (e / 640) * 640;
        bf16x8 iv = *(const bf16x8*)(src + e);
        bf16x8 pk;
        #pragma unroll
        for (int j = 0; j < 8; j++)
            pk[j] = (bf16)fmaxf(fmaf((float)iv[j], scj[j], shj[j]), 0.0f);
        size_t xidx = (((size_t)(b * 32 + cib) * 82 + row + 1) * 82) * 8 + 8 + w640;
        *(bf16x8*)(xp + xidx) = pk;
    }
}

// ---------------- final: out = relu(gn2(y2) * gate + x), NCHW f32 ---------------
__global__ __launch_bounds__(256) void final_kernel(
    const bf16* __restrict__ y, const float* __restrict__ x,
    const float* __restrict__ gate,
    const float* __restrict__ s, const float* __restrict__ sq,
    const float* __restrict__ gamma, const float* __restrict__ beta,
    float* __restrict__ out)
{
    __shared__ float lds[8 * 328];
    int bid = blockIdx.x;
    int b = bid / 640; int rem = bid - b * 640;
    int cib = rem / 20; int rq = rem - cib * 20;
    int gidx = b * 32 + cib;
    const float cnt = (float)(8 * NHW);
    float m  = s[gidx] / cnt;
    float vv = sq[gidx] / cnt - m * m;
    float r  = rsqrtf(vv + GN_EPS);
    float scj[8], shj[8];
    #pragma unroll
    for (int j = 0; j < 8; j++) {
        int c = cib * 8 + j;
        scj[j] = r * gamma[c];
        shj[j] = beta[c] - m * scj[j];
    }
    const bf16* src = y + (size_t)(b * 32 + cib) * 51200 + rq * 2560;
    for (int u = threadIdx.x; u < 320; u += 256) {
        bf16x8 iv = *(const bf16x8*)(src + u * 8);
        #pragma unroll
        for (int j = 0; j < 8; j++)
            lds[j * 328 + u] = fmaf((float)iv[j], scj[j], shj[j]);
    }
    __syncthreads();
    const float* gp = gate + b * NHW + rq * 320;
    for (int u = threadIdx.x; u < 640; u += 256) {
        int c8 = u / 80; int rc = (u - c8 * 80) * 4;
        int c = cib * 8 + c8;
        size_t oidx = (size_t)(b * NC + c) * NHW + rq * 320 + rc;
        float4 xv = *(const float4*)(x + oidx);
        float4 gv = *(const float4*)(gp + rc);
        float4 lv = *(const float4*)(&lds[c8 * 328 + rc]);
        float4 ov;
        ov.x = fmaxf(fmaf(lv.x, gv.x, xv.x), 0.0f);
        ov.y = fmaxf(fmaf(lv.y, gv.y, xv.y), 0.0f);
        ov.z = fmaxf(fmaf(lv.z, gv.z, xv.z), 0.0f);
        ov.w = fmaxf(fmaf(lv.w, gv.w, xv.w), 0.0f);
        *(float4*)(out + oidx) = ov;
    }
}

extern "C" void kernel_launch(void* const* d_in, const int* in_sizes, int n_in,
                              void* d_out, int out_size, void* d_ws, size_t ws_size,
                              hipStream_t stream)
{
    const float* x     = (const float*)d_in[0];
    const float* w1    = (const float*)d_in[1];
    const float* gn1_w = (const float*)d_in[2];
    const float* gn1_b = (const float*)d_in[3];
    const float* w2    = (const float*)d_in[4];
    const float* gn2_w = (const float*)d_in[5];
    const float* gn2_b = (const float*)d_in[6];
    const float* gw    = (const float*)d_in[7];
    const float* gb    = (const float*)d_in[8];

    // d_out (52.4 MB): xp scratch 27.54 MB | gpart scratch 6.55 MB | (final writes all)
    bf16*  xp    = (bf16*)d_out;
    float* gpart = (float*)((char*)d_out + 27541504);
    float* out   = (float*)d_out;

    char* wsb = (char*)d_ws;
    bf16*  y     = (bf16*)wsb;                                   // 26,214,400 B
    float* gate  = (float*)(wsb + 26214400);                     //    204,800 B
    bf16*  wA1   = (bf16*)(wsb + 26214400 + 204800);             //  1,179,648 B
    bf16*  wA2   = wA1 + 589824;                                 //  1,179,648 B
    float* stats = (float*)(wsb + 26214400 + 204800 + 2 * 1179648);
    float* s1  = stats,        * s1q = stats + 256;
    float* s2  = stats + 1024, * s2q = stats + 1280;

    prep_kernel<<<9729, 256, 0, stream>>>(x, xp, gw, gpart, w1, w2, wA1, wA2, stats);
    conv_kernel<<<640, 256, 0, stream>>>(xp, wA1, y, s1, s1q);
    prep2_kernel<<<5320, 256, 0, stream>>>(y, xp, s1, s1q, gn1_w, gn1_b, gpart, gb, gate);
    conv_kernel<<<640, 256, 0, stream>>>(xp, wA2, y, s2, s2q);
    final_kernel<<<5120, 256, 0, stream>>>(y, x, gate, s2, s2q, gn2_w, gn2_b, out);
}